// Round 3
// baseline (11985.418 us; speedup 1.0000x reference)
//
#include <hip/hip_runtime.h>

#define BB 128   // batch
#define SS 128   // seq
#define EE 256   // enc dim
#define DD 256   // lstm hidden
#define OO 64    // out dim

// LDS pool layout (float offsets)
#define POOLA   0      // 8448: xl/ytl [64][132] (phaseA/C), Wel [32][256] (encproj)
#define POOLB   8448   // 1152: hc-parts / red / g  (stride-9 [128][9] or [4][256])
#define ILOFF   9600   // 4608: il [128][36] (encproj only; overlaps weight LDS below)
#define WLOFF   9600   // 2080: wl  [8][260]  Whh cols (init after encproj)
#define W1LOFF  11680  // 1032: w1l [2][516]  W1 cols
#define WIHLOFF 12712  //  544: wihl[8][68]   Wih cols
#define W2LOFF  14208  //  256
#define HCLOFF  14464  //  256
#define CTXLOFF 14720  //  256
#define ARAWOFF 14976  //  128
#define YLOFF   15104  //   64
#define FCBLOFF 15168  //   64
#define BSLOFF  15232  //    8
#define B1LOFF  15240  //    2
#define MISCOFF 15242  //    2
#define PSIZE   15244  // 60976 B < 64 KB

__device__ __forceinline__ float fsig(float x) { return 1.0f / (1.0f + __expf(-x)); }
__device__ __forceinline__ float ftanh(float x) {
    float t = __expf(-2.0f * fabsf(x));
    float r = (1.0f - t) / (1.0f + t);
    return copysignf(r, x);
}

__device__ __forceinline__ void grid_sync(int* cnt, int* sense, int* lsense) {
    __syncthreads();
    if (threadIdx.x == 0) {
        int s = *lsense ^ 1;
        *lsense = s;
        __threadfence();  // agent-scope release of prior writes
        int a = __hip_atomic_fetch_add(cnt, 1, __ATOMIC_ACQ_REL, __HIP_MEMORY_SCOPE_AGENT);
        if (a == BB - 1) {
            __hip_atomic_store(cnt, 0, __ATOMIC_RELAXED, __HIP_MEMORY_SCOPE_AGENT);
            __hip_atomic_store(sense, s, __ATOMIC_RELEASE, __HIP_MEMORY_SCOPE_AGENT);
        } else {
            while (__hip_atomic_load(sense, __ATOMIC_ACQUIRE, __HIP_MEMORY_SCOPE_AGENT) != s)
                __builtin_amdgcn_s_sleep(2);
        }
    }
    __syncthreads();
}

// Persistent kernel: 128 blocks x 1024 threads, 1 block/CU guaranteed by
// __launch_bounds__(1024,4) (VGPR<=128, 16 waves = whole CU) + grid 128 <= 256 CUs.
// Block is BOTH row-owner b=blockIdx.x (attention) and col-owner j=blockIdx.x
// (gate cols {q*256+2j+d2}, hc cols {2j,2j+1}).
__global__ __launch_bounds__(1024, 4) void scan_kernel(
    const float* __restrict__ inp,   // B,S,E
    const float* __restrict__ yhist, // B,S,OO
    const float* __restrict__ h0, const float* __restrict__ c0,
    const float* __restrict__ W1,    // 768x256 rows: Wh|Wc|We
    const float* __restrict__ b1, const float* __restrict__ w2, const float* __restrict__ b2,
    const float* __restrict__ Wih,   // 64x1024
    const float* __restrict__ Whh,   // 256x1024
    const float* __restrict__ bih, const float* __restrict__ bhh,
    const float* __restrict__ fcW,   // 320x64
    const float* __restrict__ fcb,   // 64
    float* __restrict__ hctxT,       // ws: [512][128]  (rows 0..255 = h, 256..511 = ctx)
    float* __restrict__ scratch,     // d_out-scratch: cT[256][128] | hcgl[128][256] | ytT[64][128]
    int* __restrict__ bar)           // d_out-scratch: cnt at +0, sense at +16 ints
{
    __shared__ float P[PSIZE];
    const int b = blockIdx.x;   // row role
    const int j = blockIdx.x;   // col role
    const int t = threadIdx.x;
    float* hT   = hctxT;
    float* cT   = scratch;
    float* hcgl = scratch + 32768;
    float* ytT  = scratch + 65536;
    int* cnt = bar; int* sense = bar + 16;
    int lsense = 0;

    const float* inp_b = inp + b * SS * EE;
    const float b2v = b2[0];
    const int sub = t & 31, sgrp = t >> 5;        // scores role: s = sgrp*4+i, e = sub+32*jj
    const int idx = t & 7,  bg  = (t >> 3) & 31;  // gh/gates role (t<256): b = bg*4+r, col = col(idx)
    const int hcc = t & 1,  hbg = (t >> 1) & 31, hks = (t >> 6) & 3; // hc role (256<=t<512)

    // ---- init h/c (transposed) ----
    if (t < 256) {
        hT[t * 128 + b] = h0[b * 256 + t];
        cT[t * 128 + b] = c0[b * 256 + t];
    }

    // ---- enc_proj into registers: er[i][jj] = enc_proj[s=sgrp*4+i][e=sub+32*jj] ----
    float er[4][8];
    #pragma unroll
    for (int i = 0; i < 4; ++i)
        #pragma unroll
        for (int jj = 0; jj < 8; ++jj) er[i][jj] = 0.f;
    for (int kc = 0; kc < 8; ++kc) {
        // Wel: We rows [kc*32, +32) x 256  -> POOLA [32][256]
        #pragma unroll
        for (int i = 0; i < 2; ++i) {
            const int flat4 = t + i * 1024;
            const int row = flat4 >> 6, e4 = (flat4 & 63) * 4;
            float4 v = *(const float4*)(W1 + (size_t)(512 + kc * 32 + row) * 256 + e4);
            *(float4*)&P[POOLA + row * 256 + e4] = v;
        }
        // il: inp[b][s][kc*32 + k4..] -> [128][36]
        {
            const int s = t >> 3, k4 = (t & 7) * 4;
            float4 v = *(const float4*)(inp_b + s * 256 + kc * 32 + k4);
            *(float4*)&P[ILOFF + s * 36 + k4] = v;
        }
        __syncthreads();
        for (int kk = 0; kk < 32; ++kk) {
            float xv[4];
            #pragma unroll
            for (int i = 0; i < 4; ++i) xv[i] = P[ILOFF + (sgrp * 4 + i) * 36 + kk];
            #pragma unroll
            for (int jj = 0; jj < 8; ++jj) {
                const float wv = P[POOLA + kk * 256 + sub + 32 * jj];
                #pragma unroll
                for (int i = 0; i < 4; ++i) er[i][jj] += xv[i] * wv;
            }
        }
        __syncthreads();
    }

    // ---- weight LDS init (clobbers il region) ----
    #pragma unroll
    for (int i = 0; i < 2; ++i) {      // wl: Whh[k][col(idx)]
        const int flat = t + i * 1024;
        const int i8 = flat & 7, k = flat >> 3;
        const int col = (i8 >> 1) * 256 + 2 * j + (i8 & 1);
        P[WLOFF + i8 * 260 + k] = Whh[k * 1024 + col];
    }
    {                                   // w1l: W1[k][2j+cc]
        const int cc = t >> 9, k = t & 511;
        P[W1LOFF + cc * 516 + k] = W1[k * 256 + 2 * j + cc];
    }
    if (t < 512) {                      // wihl
        const int i8 = t & 7, k = t >> 3;
        const int col = (i8 >> 1) * 256 + 2 * j + (i8 & 1);
        P[WIHLOFF + i8 * 68 + k] = Wih[k * 1024 + col];
    }
    if (t < 256) P[W2LOFF + t] = w2[t];
    if (t < 64)  P[FCBLOFF + t] = fcb[t];
    if (t < 8) {
        const int col = (t >> 1) * 256 + 2 * j + (t & 1);
        P[BSLOFF + t] = bih[col] + bhh[col];
    }
    if (t < 2)   P[B1LOFF + t] = b1[2 * j + t];
    grid_sync(cnt, sense, &lsense);

    float ghacc[4];
    for (int ts = 0; ts < SS; ++ts) {
        // ================= PHASE A (column roles) =================
        #pragma unroll
        for (int r = 0; r < 4; ++r) ghacc[r] = 0.f;
        float hcacc[4] = {0.f, 0.f, 0.f, 0.f};
        for (int kc = 0; kc < 4; ++kc) {   // h rows [kc*64,+64) -> POOLA [64][132]
            #pragma unroll
            for (int i = 0; i < 2; ++i) {
                const int flat4 = t + i * 1024;
                const int row = flat4 >> 5, b4 = (flat4 & 31) * 4;
                float4 v = *(const float4*)(hT + (size_t)(kc * 64 + row) * 128 + b4);
                *(float4*)&P[POOLA + row * 132 + b4] = v;
            }
            __syncthreads();
            if (t < 256) {           // gh accumulate from LDS chunk
                #pragma unroll
                for (int k4 = 0; k4 < 16; ++k4) {
                    const float4 w4 = *(const float4*)&P[WLOFF + idx * 260 + kc * 64 + k4 * 4];
                    const float wv[4] = {w4.x, w4.y, w4.z, w4.w};
                    #pragma unroll
                    for (int kk = 0; kk < 4; ++kk) {
                        const float4 x4 = *(const float4*)&P[POOLA + (k4 * 4 + kk) * 132 + bg * 4];
                        ghacc[0] += x4.x * wv[kk]; ghacc[1] += x4.y * wv[kk];
                        ghacc[2] += x4.z * wv[kk]; ghacc[3] += x4.w * wv[kk];
                    }
                }
            } else if (t < 512) {    // hc: 8 of 32 k4-iters per chunk-slot, global x
                #pragma unroll
                for (int q4 = 0; q4 < 8; ++q4) {
                    const int k4 = kc * 8 + q4;
                    const int kglob = hks * 128 + k4 * 4;
                    const float4 w4 = *(const float4*)&P[W1LOFF + hcc * 516 + kglob];
                    const float wv[4] = {w4.x, w4.y, w4.z, w4.w};
                    const float* xrow = (hks < 2) ? (hT + (size_t)kglob * 128)
                                                  : (cT + (size_t)(kglob - 256) * 128);
                    #pragma unroll
                    for (int kk = 0; kk < 4; ++kk) {
                        const float4 x4 = *(const float4*)(xrow + kk * 128 + hbg * 4);
                        hcacc[0] += x4.x * wv[kk]; hcacc[1] += x4.y * wv[kk];
                        hcacc[2] += x4.z * wv[kk]; hcacc[3] += x4.w * wv[kk];
                    }
                }
            }
            __syncthreads();
        }
        if (t >= 256 && t < 512) {
            #pragma unroll
            for (int r = 0; r < 4; ++r)
                P[POOLB + (hbg * 4 + r) * 9 + hcc * 4 + hks] = hcacc[r];
        }
        __syncthreads();
        if (t < 256) {   // reduce hc parts + b1 -> hcgl (b-major)
            const int bb = t >> 1, cc2 = t & 1;
            float v = P[B1LOFF + cc2];
            #pragma unroll
            for (int ks = 0; ks < 4; ++ks) v += P[POOLB + bb * 9 + cc2 * 4 + ks];
            hcgl[bb * 256 + 2 * j + cc2] = v;
        }
        grid_sync(cnt, sense, &lsense);

        // ================= PHASE B (row b) =================
        if (t < 64) {
            float4 hv = *(const float4*)(hcgl + b * 256 + t * 4);
            *(float4*)&P[HCLOFF + t * 4] = hv;
            P[YLOFF + t] = yhist[b * (SS * OO) + ts * OO + t];
        }
        __syncthreads();
        // scores (tanh) + per-group reduce
        {
            float sa[4] = {0.f, 0.f, 0.f, 0.f};
            #pragma unroll
            for (int jj = 0; jj < 8; ++jj) {
                const int e = sub + 32 * jj;
                const float hce = P[HCLOFF + e], w2e = P[W2LOFF + e];
                #pragma unroll
                for (int i = 0; i < 4; ++i) sa[i] += ftanh(er[i][jj] + hce) * w2e;
            }
            #pragma unroll
            for (int m = 16; m > 0; m >>= 1)
                #pragma unroll
                for (int i = 0; i < 4; ++i) sa[i] += __shfl_xor(sa[i], m);
            if (sub == 0) {
                #pragma unroll
                for (int i = 0; i < 4; ++i)
                    P[ARAWOFF + sgrp * 4 + i] = __expf(sa[i] + b2v);  // max-free: |score|<~10
            }
        }
        __syncthreads();
        if (t < 64) {
            float v = P[ARAWOFF + t] + P[ARAWOFF + t + 64];
            #pragma unroll
            for (int m = 32; m > 0; m >>= 1) v += __shfl_xor(v, m);
            if (t == 0) P[MISCOFF] = 1.0f / v;
        }
        __syncthreads();
        // context partials over s-chunks
        {
            const int e = t & 255, scq = t >> 8;
            float a = 0.f;
            for (int s = scq * 32; s < scq * 32 + 32; ++s)
                a += P[ARAWOFF + s] * inp_b[s * 256 + e];
            P[POOLB + scq * 256 + e] = a;
        }
        __syncthreads();
        if (t < 256) {
            const float v = (P[POOLB + t] + P[POOLB + 256 + t] +
                             P[POOLB + 512 + t] + P[POOLB + 768 + t]) * P[MISCOFF];
            P[CTXLOFF + t] = v;
            if (ts == SS - 1) hctxT[(size_t)(256 + t) * 128 + b] = v;
        }
        __syncthreads();
        // y_tilde = [ctx|y]@fcW + fcb
        if (t < 512) {
            const int o = t & 63, c8 = t >> 6;
            float a = 0.f;
            for (int kk = c8 * 40; kk < c8 * 40 + 40; ++kk) {
                const float val = (kk < 256) ? P[CTXLOFF + kk] : P[YLOFF + kk - 256];
                a += val * fcW[kk * 64 + o];
            }
            P[POOLB + c8 * 64 + o] = a;
        }
        __syncthreads();
        if (t < 64) {
            float v = P[FCBLOFF + t];
            #pragma unroll
            for (int c8 = 0; c8 < 8; ++c8) v += P[POOLB + c8 * 64 + t];
            ytT[t * 128 + b] = v;   // transposed for phase C staging
        }
        grid_sync(cnt, sense, &lsense);

        // ================= PHASE C (column roles) =================
        #pragma unroll
        for (int i = 0; i < 2; ++i) {   // stage ytT -> POOLA [64][132]
            const int flat4 = t + i * 1024;
            const int row = flat4 >> 5, b4 = (flat4 & 31) * 4;
            float4 v = *(const float4*)(ytT + row * 128 + b4);
            *(float4*)&P[POOLA + row * 132 + b4] = v;
        }
        __syncthreads();
        if (t < 256) {
            float g[4];
            #pragma unroll
            for (int r = 0; r < 4; ++r) g[r] = ghacc[r] + P[BSLOFF + idx];
            #pragma unroll
            for (int k4 = 0; k4 < 16; ++k4) {
                const float4 w4 = *(const float4*)&P[WIHLOFF + idx * 68 + k4 * 4];
                const float wv[4] = {w4.x, w4.y, w4.z, w4.w};
                #pragma unroll
                for (int kk = 0; kk < 4; ++kk) {
                    const float4 x4 = *(const float4*)&P[POOLA + (k4 * 4 + kk) * 132 + bg * 4];
                    g[0] += x4.x * wv[kk]; g[1] += x4.y * wv[kk];
                    g[2] += x4.z * wv[kk]; g[3] += x4.w * wv[kk];
                }
            }
            #pragma unroll
            for (int r = 0; r < 4; ++r) P[POOLB + (bg * 4 + r) * 9 + idx] = g[r];
        }
        __syncthreads();
        if (t < 256) {   // LSTM pointwise for d-cols {2j, 2j+1}
            const int bb = t >> 1, d2 = t & 1;
            const int dcol = 2 * j + d2;
            const float gi = P[POOLB + bb * 9 + d2];
            const float gf = P[POOLB + bb * 9 + 2 + d2];
            const float gg = P[POOLB + bb * 9 + 4 + d2];
            const float go = P[POOLB + bb * 9 + 6 + d2];
            const float co = cT[dcol * 128 + bb];
            const float cn = fsig(gf) * co + fsig(gi) * ftanh(gg);
            cT[dcol * 128 + bb] = cn;
            hT[dcol * 128 + bb] = fsig(go) * ftanh(cn);
        }
        grid_sync(cnt, sense, &lsense);
    }
}

// out(128 x 8192) = A(128x512, stored transposed AT[512][128]) @ W(512x8192) + bias
__global__ __launch_bounds__(256) void out_gemm(
    const float* __restrict__ AT, const float* __restrict__ W,
    const float* __restrict__ bias, float* __restrict__ out)
{
    __shared__ float Ab[64 * 132];  // [k][m]
    __shared__ float Bb[64 * 32];   // [k][n]
    const int t = threadIdx.x;
    const int nt = blockIdx.x * 32;
    const int n4 = (t & 7) * 4;
    const int m4 = (t >> 3) * 4;
    float acc[4][4];
    #pragma unroll
    for (int i = 0; i < 4; ++i)
        #pragma unroll
        for (int jj = 0; jj < 4; ++jj) acc[i][jj] = 0.f;

    for (int kc = 0; kc < 8; ++kc) {
        #pragma unroll
        for (int i = 0; i < 8; ++i) {
            const int flat4 = i * 256 + t;
            const int row = flat4 >> 5, mm4 = (flat4 & 31) * 4;
            float4 v = *(const float4*)(AT + (size_t)(kc * 64 + row) * 128 + mm4);
            *(float4*)&Ab[row * 132 + mm4] = v;
        }
        #pragma unroll
        for (int i = 0; i < 2; ++i) {
            const int fl = t + i * 256;
            const int k = fl >> 3, nn4 = (fl & 7) * 4;
            *(float4*)&Bb[k * 32 + nn4] =
                *(const float4*)(W + (size_t)(kc * 64 + k) * 8192 + nt + nn4);
        }
        __syncthreads();
        for (int k = 0; k < 64; ++k) {
            const float4 bv = *(const float4*)&Bb[k * 32 + n4];
            const float4 av = *(const float4*)&Ab[k * 132 + m4];
            acc[0][0] += av.x * bv.x; acc[0][1] += av.x * bv.y; acc[0][2] += av.x * bv.z; acc[0][3] += av.x * bv.w;
            acc[1][0] += av.y * bv.x; acc[1][1] += av.y * bv.y; acc[1][2] += av.y * bv.z; acc[1][3] += av.y * bv.w;
            acc[2][0] += av.z * bv.x; acc[2][1] += av.z * bv.y; acc[2][2] += av.z * bv.z; acc[2][3] += av.z * bv.w;
            acc[3][0] += av.w * bv.x; acc[3][1] += av.w * bv.y; acc[3][2] += av.w * bv.z; acc[3][3] += av.w * bv.w;
        }
        __syncthreads();
    }
    const float4 bb = *(const float4*)(bias + nt + n4);
    #pragma unroll
    for (int i = 0; i < 4; ++i) {
        float4 r;
        r.x = acc[i][0] + bb.x; r.y = acc[i][1] + bb.y;
        r.z = acc[i][2] + bb.z; r.w = acc[i][3] + bb.w;
        *(float4*)(out + (size_t)(m4 + i) * 8192 + nt + n4) = r;
    }
}

extern "C" void kernel_launch(void* const* d_in, const int* in_sizes, int n_in,
                              void* d_out, int out_size, void* d_ws, size_t ws_size,
                              hipStream_t stream) {
    const float* inp = (const float*)d_in[0];
    const float* yh  = (const float*)d_in[1];
    const float* h0  = (const float*)d_in[2];
    const float* c0  = (const float*)d_in[3];
    const float* W1  = (const float*)d_in[4];
    const float* b1  = (const float*)d_in[5];
    const float* w2  = (const float*)d_in[6];
    const float* b2  = (const float*)d_in[7];
    const float* Wih = (const float*)d_in[8];
    const float* Whh = (const float*)d_in[9];
    const float* bih = (const float*)d_in[10];
    const float* bhh = (const float*)d_in[11];
    const float* fcW = (const float*)d_in[12];
    const float* fcb = (const float*)d_in[13];
    const float* foW = (const float*)d_in[14];
    const float* fob = (const float*)d_in[15];

    float* hctxT = (float*)d_ws;                       // 512*128 floats = 256 KB (proven size)
    float* scr   = (float*)d_out;                      // cT | hcgl | ytT in d_out scratch
    int*   bar   = (int*)((char*)d_out + 294912);      // barrier words, after ytT, before 1.2MB

    hipMemsetAsync(bar, 0, 128, stream);               // zero cnt+sense each launch
    scan_kernel<<<dim3(BB), dim3(1024), 0, stream>>>(
        inp, yh, h0, c0, W1, b1, w2, b2, Wih, Whh, bih, bhh, fcW, fcb,
        hctxT, scr, bar);
    out_gemm<<<dim3(8192 / 32), dim3(256), 0, stream>>>(hctxT, foW, fob, (float*)d_out);
}

// Round 4
// 4857.193 us; speedup vs baseline: 2.4676x; 2.4676x over previous
//
#include <hip/hip_runtime.h>

#define BB 128   // batch
#define SS 128   // seq
#define EE 256   // enc dim
#define DD 256   // lstm hidden
#define OO 64    // out dim

// bf16 weight buffer layout (ushort offsets) inside d_out scratch
#define W1_OFF   0         // 768*256   = 196608 (rows: Wh|Wc|We)
#define WHH_OFF  196608    // 256*1024  = 262144
#define WIH_OFF  458752    // 64*1024   = 65536
#define FCW_OFF  524288    // 320*64    = 20480
#define WTOTAL   544768

__device__ __forceinline__ float fsig(float x) { return 1.0f / (1.0f + __expf(-x)); }
__device__ __forceinline__ float ftanh(float x) {
    float t = __expf(-2.0f * fabsf(x));
    float r = (1.0f - t) / (1.0f + t);
    return copysignf(r, x);
}
// swizzle within 32-float groups (rotation by 4*(group)): conflict-free strided access
__device__ __forceinline__ int SWZ(int e) { return (e & ~31) | ((e + 4 * (e >> 5)) & 31); }

__device__ __forceinline__ void fma8(const uint4 w, const float xv, float* acc) {
    acc[0] += xv * __uint_as_float(w.x << 16);
    acc[1] += xv * __uint_as_float(w.x & 0xffff0000u);
    acc[2] += xv * __uint_as_float(w.y << 16);
    acc[3] += xv * __uint_as_float(w.y & 0xffff0000u);
    acc[4] += xv * __uint_as_float(w.z << 16);
    acc[5] += xv * __uint_as_float(w.z & 0xffff0000u);
    acc[6] += xv * __uint_as_float(w.w << 16);
    acc[7] += xv * __uint_as_float(w.w & 0xffff0000u);
}

// fp32 -> bf16 (RNE) weight conversion, runs every launch (graph-safe, same work)
__global__ __launch_bounds__(256) void conv_kernel(
    const float* __restrict__ W1, const float* __restrict__ Whh,
    const float* __restrict__ Wih, const float* __restrict__ fcW,
    unsigned short* __restrict__ out)
{
    const int idx = blockIdx.x * 256 + threadIdx.x;
    float f;
    if      (idx < WHH_OFF)  f = W1[idx];
    else if (idx < WIH_OFF)  f = Whh[idx - WHH_OFF];
    else if (idx < FCW_OFF)  f = Wih[idx - WIH_OFF];
    else if (idx < WTOTAL)   f = fcW[idx - FCW_OFF];
    else return;
    unsigned int u = __float_as_uint(f);
    u = (u + 0x7fffu + ((u >> 16) & 1u)) >> 16;
    out[idx] = (unsigned short)u;
}

// One block (1024 thr, 16 waves) per batch row; whole scan block-local.
__global__ __launch_bounds__(1024, 4) void scan_kernel(
    const float* __restrict__ inp,   // B,S,E
    const float* __restrict__ yhist, // B,S,OO
    const float* __restrict__ h0, const float* __restrict__ c0,
    const float* __restrict__ W1f,   // fp32 W1 (only We rows used here, init)
    const float* __restrict__ b1, const float* __restrict__ w2, const float* __restrict__ b2,
    const float* __restrict__ bih, const float* __restrict__ bhh,
    const float* __restrict__ fcb,
    const unsigned short* __restrict__ wbf,  // bf16 weights (see *_OFF)
    float* __restrict__ hctxT)       // ws: [512][128] (0..255 h, 256..511 ctx)
{
    __shared__ float sh_h[DD], sh_c[DD], sh_hc[EE];      // sh_hc stored SWZ'd
    __shared__ float sh_gh[1024];
    __shared__ float sh_w2[EE];                          // SWZ'd
    __shared__ float sh_b1[EE], sh_bs[1024];
    __shared__ float sh_raw[SS];                         // exp(scores)
    __shared__ float sh_ctx[EE], sh_y[OO], sh_yt[OO], sh_fcb[OO];
    __shared__ float sh_misc[1];
    __shared__ float red1[32 * 256];                     // 8192
    __shared__ float red2[8 * 1024];                     // 8192

    const int b = blockIdx.x, t = threadIdx.x;
    const float* inp_b = inp + b * SS * EE;
    const unsigned short* W1bf  = wbf + W1_OFF;
    const unsigned short* Whhbf = wbf + WHH_OFF;
    const unsigned short* Wihbf = wbf + WIH_OFF;
    const unsigned short* fcWbf = wbf + FCW_OFF;
    const float b2v = b2[0];

    // role constants
    const int e8  = (t & 31) * 8,  kc1 = t >> 5;   // P1
    const int j8  = (t & 127) * 8, kc2 = t >> 7;   // P1b / P4
    const int s_own = t >> 3,      a2  = t & 7, e0 = a2 * 32;  // P2
    const int e4  = (t & 63) * 4,  sc  = t >> 6;   // P3
    const int o4  = (t & 15) * 4,  kc3 = t >> 4;   // P3b

    if (t < 256) {
        sh_h[t] = h0[b * 256 + t]; sh_c[t] = c0[b * 256 + t];
        sh_b1[t] = b1[t];
        sh_w2[SWZ(t)] = w2[t];
    }
    if (t < 64) sh_fcb[t] = fcb[t];
    sh_bs[t] = bih[t] + bhh[t];

    // ---- enc_proj into registers via LDS-staged chunks (fp32 We, one-time) ----
    float er[32];
    #pragma unroll
    for (int j = 0; j < 32; ++j) er[j] = 0.f;
    {
        const float* We = W1f + 512 * 256;
        for (int kc = 0; kc < 16; ++kc) {
            {   // stage We rows [kc*16,+16) x 256 -> red1[0..4095]
                const int row = t >> 6, c4 = (t & 63) * 4;
                float4 v = *(const float4*)(We + (size_t)(kc * 16 + row) * 256 + c4);
                *(float4*)&red1[row * 256 + c4] = v;
            }
            {   // stage inp cols [kc*16,+16) for all 128 s -> red1[4096..6143]
                const int s = t >> 3, k2 = (t & 7) * 2;
                float2 v = *(const float2*)(inp_b + s * 256 + kc * 16 + k2);
                red1[4096 + s * 16 + k2] = v.x;
                red1[4096 + s * 16 + k2 + 1] = v.y;
            }
            __syncthreads();
            for (int k = 0; k < 16; ++k) {
                const float xv = red1[4096 + s_own * 16 + k];
                #pragma unroll
                for (int j4 = 0; j4 < 8; ++j4) {
                    float4 w = *(const float4*)&red1[k * 256 + e0 + j4 * 4];
                    er[j4*4+0] += xv * w.x; er[j4*4+1] += xv * w.y;
                    er[j4*4+2] += xv * w.z; er[j4*4+3] += xv * w.w;
                }
            }
            __syncthreads();
        }
    }

    for (int ts = 0; ts < SS; ++ts) {
        if (t < 64) sh_y[t] = yhist[b * SS * OO + ts * OO + t];

        // ---- P1: hc partials [32][256] -> red1
        {
            float acc[8];
            #pragma unroll
            for (int r = 0; r < 8; ++r) acc[r] = 0.f;
            #pragma unroll 4
            for (int k = kc1 * 16; k < kc1 * 16 + 16; ++k) {
                const float xv = (k < 256) ? sh_h[k] : sh_c[k - 256];
                uint4 w = *(const uint4*)(W1bf + (size_t)k * 256 + e8);
                fma8(w, xv, acc);
            }
            *(float4*)&red1[kc1 * 256 + e8]     = make_float4(acc[0], acc[1], acc[2], acc[3]);
            *(float4*)&red1[kc1 * 256 + e8 + 4] = make_float4(acc[4], acc[5], acc[6], acc[7]);
        }
        // ---- P1b: gh partials [8][1024] -> red2
        {
            float acc[8];
            #pragma unroll
            for (int r = 0; r < 8; ++r) acc[r] = 0.f;
            #pragma unroll 4
            for (int k = kc2 * 32; k < kc2 * 32 + 32; ++k) {
                const float hv = sh_h[k];
                uint4 w = *(const uint4*)(Whhbf + (size_t)k * 1024 + j8);
                fma8(w, hv, acc);
            }
            *(float4*)&red2[kc2 * 1024 + j8]     = make_float4(acc[0], acc[1], acc[2], acc[3]);
            *(float4*)&red2[kc2 * 1024 + j8 + 4] = make_float4(acc[4], acc[5], acc[6], acc[7]);
        }
        __syncthreads();
        if (t < 256) {
            float v = sh_b1[t];
            #pragma unroll 8
            for (int kc = 0; kc < 32; ++kc) v += red1[kc * 256 + t];
            sh_hc[SWZ(t)] = v;
        }
        {
            float v = 0.f;
            #pragma unroll
            for (int kc = 0; kc < 8; ++kc) v += red2[kc * 1024 + t];
            sh_gh[t] = v;
        }
        __syncthreads();

        // ---- P2: scores from register er + swizzled hc/w2 (conflict-free)
        {
            float acc = 0.f;
            #pragma unroll
            for (int j4 = 0; j4 < 8; ++j4) {
                const int phys = e0 + ((j4 * 4 + 4 * a2) & 31);
                float4 hc4 = *(const float4*)&sh_hc[phys];
                float4 w24 = *(const float4*)&sh_w2[phys];
                acc += ftanh(er[j4*4+0] + hc4.x) * w24.x;
                acc += ftanh(er[j4*4+1] + hc4.y) * w24.y;
                acc += ftanh(er[j4*4+2] + hc4.z) * w24.z;
                acc += ftanh(er[j4*4+3] + hc4.w) * w24.w;
            }
            acc += __shfl_xor(acc, 1);
            acc += __shfl_xor(acc, 2);
            acc += __shfl_xor(acc, 4);
            if (a2 == 0) sh_raw[s_own] = __expf(acc + b2v);  // max-free: |score| <= sum|w2| ~ 10
        }
        __syncthreads();
        if (t < 64) {
            float v = sh_raw[t] + sh_raw[t + 64];
            #pragma unroll
            for (int m = 32; m > 0; m >>= 1) v += __shfl_xor(v, m);
            if (t == 0) sh_misc[0] = 1.0f / v;
        }
        __syncthreads();

        // ---- P3: context partials [16][256] -> red1
        {
            float ax = 0.f, ay = 0.f, az = 0.f, aw = 0.f;
            for (int s = sc * 8; s < sc * 8 + 8; ++s) {
                const float al = sh_raw[s];
                float4 iv = *(const float4*)(inp_b + s * 256 + e4);
                ax += al * iv.x; ay += al * iv.y; az += al * iv.z; aw += al * iv.w;
            }
            *(float4*)&red1[sc * 256 + e4] = make_float4(ax, ay, az, aw);
        }
        __syncthreads();
        if (t < 256) {
            float v = 0.f;
            #pragma unroll
            for (int k = 0; k < 16; ++k) v += red1[k * 256 + t];
            v *= sh_misc[0];
            sh_ctx[t] = v;
            if (ts == SS - 1) hctxT[(size_t)(256 + t) * 128 + b] = v;
        }
        __syncthreads();

        // ---- P3b: y_tilde partials [64][64] -> red1
        {
            float acc[4] = {0.f, 0.f, 0.f, 0.f};
            for (int kk = kc3 * 5; kk < kc3 * 5 + 5; ++kk) {
                const float val = (kk < 256) ? sh_ctx[kk] : sh_y[kk - 256];
                uint2 w = *(const uint2*)(fcWbf + kk * 64 + o4);
                acc[0] += val * __uint_as_float(w.x << 16);
                acc[1] += val * __uint_as_float(w.x & 0xffff0000u);
                acc[2] += val * __uint_as_float(w.y << 16);
                acc[3] += val * __uint_as_float(w.y & 0xffff0000u);
            }
            *(float4*)&red1[kc3 * 64 + o4] = make_float4(acc[0], acc[1], acc[2], acc[3]);
        }
        __syncthreads();
        if (t < 64) {
            float v = sh_fcb[t];
            #pragma unroll 16
            for (int kc = 0; kc < 64; ++kc) v += red1[kc * 64 + t];
            sh_yt[t] = v;
        }
        __syncthreads();

        // ---- P4: gate partials (Wih) [8][1024] -> red2
        {
            float acc[8];
            #pragma unroll
            for (int r = 0; r < 8; ++r) acc[r] = 0.f;
            #pragma unroll
            for (int k = kc2 * 8; k < kc2 * 8 + 8; ++k) {
                const float yv = sh_yt[k];
                uint4 w = *(const uint4*)(Wihbf + (size_t)k * 1024 + j8);
                fma8(w, yv, acc);
            }
            *(float4*)&red2[kc2 * 1024 + j8]     = make_float4(acc[0], acc[1], acc[2], acc[3]);
            *(float4*)&red2[kc2 * 1024 + j8 + 4] = make_float4(acc[4], acc[5], acc[6], acc[7]);
        }
        __syncthreads();
        {
            float v = sh_gh[t] + sh_bs[t];
            #pragma unroll
            for (int kc = 0; kc < 8; ++kc) v += red2[kc * 1024 + t];
            red1[t] = v;   // gates[1024]
        }
        __syncthreads();
        if (t < 256) {
            const float gi = red1[t], gf = red1[256 + t], gg = red1[512 + t], go = red1[768 + t];
            const float cn = fsig(gf) * sh_c[t] + fsig(gi) * ftanh(gg);
            sh_c[t] = cn;
            const float hn = fsig(go) * ftanh(cn);
            sh_h[t] = hn;
            if (ts == SS - 1) hctxT[(size_t)t * 128 + b] = hn;
        }
        __syncthreads();
    }
}

// out(128 x 8192) = A(128x512, stored transposed AT[512][128]) @ W(512x8192) + bias
__global__ __launch_bounds__(256) void out_gemm(
    const float* __restrict__ AT, const float* __restrict__ W,
    const float* __restrict__ bias, float* __restrict__ out)
{
    __shared__ float Ab[64 * 132];  // [k][m]
    __shared__ float Bb[64 * 32];   // [k][n]
    const int t = threadIdx.x;
    const int nt = blockIdx.x * 32;
    const int n4 = (t & 7) * 4;
    const int m4 = (t >> 3) * 4;
    float acc[4][4];
    #pragma unroll
    for (int i = 0; i < 4; ++i)
        #pragma unroll
        for (int jj = 0; jj < 4; ++jj) acc[i][jj] = 0.f;

    for (int kc = 0; kc < 8; ++kc) {
        #pragma unroll
        for (int i = 0; i < 8; ++i) {
            const int flat4 = i * 256 + t;
            const int row = flat4 >> 5, mm4 = (flat4 & 31) * 4;
            float4 v = *(const float4*)(AT + (size_t)(kc * 64 + row) * 128 + mm4);
            *(float4*)&Ab[row * 132 + mm4] = v;
        }
        #pragma unroll
        for (int i = 0; i < 2; ++i) {
            const int fl = t + i * 256;
            const int k = fl >> 3, nn4 = (fl & 7) * 4;
            *(float4*)&Bb[k * 32 + nn4] =
                *(const float4*)(W + (size_t)(kc * 64 + k) * 8192 + nt + nn4);
        }
        __syncthreads();
        for (int k = 0; k < 64; ++k) {
            const float4 bv = *(const float4*)&Bb[k * 32 + n4];
            const float4 av = *(const float4*)&Ab[k * 132 + m4];
            acc[0][0] += av.x * bv.x; acc[0][1] += av.x * bv.y; acc[0][2] += av.x * bv.z; acc[0][3] += av.x * bv.w;
            acc[1][0] += av.y * bv.x; acc[1][1] += av.y * bv.y; acc[1][2] += av.y * bv.z; acc[1][3] += av.y * bv.w;
            acc[2][0] += av.z * bv.x; acc[2][1] += av.z * bv.y; acc[2][2] += av.z * bv.z; acc[2][3] += av.z * bv.w;
            acc[3][0] += av.w * bv.x; acc[3][1] += av.w * bv.y; acc[3][2] += av.w * bv.z; acc[3][3] += av.w * bv.w;
        }
        __syncthreads();
    }
    const float4 bb = *(const float4*)(bias + nt + n4);
    #pragma unroll
    for (int i = 0; i < 4; ++i) {
        float4 r;
        r.x = acc[i][0] + bb.x; r.y = acc[i][1] + bb.y;
        r.z = acc[i][2] + bb.z; r.w = acc[i][3] + bb.w;
        *(float4*)(out + (size_t)(m4 + i) * 8192 + nt + n4) = r;
    }
}

extern "C" void kernel_launch(void* const* d_in, const int* in_sizes, int n_in,
                              void* d_out, int out_size, void* d_ws, size_t ws_size,
                              hipStream_t stream) {
    const float* inp = (const float*)d_in[0];
    const float* yh  = (const float*)d_in[1];
    const float* h0  = (const float*)d_in[2];
    const float* c0  = (const float*)d_in[3];
    const float* W1  = (const float*)d_in[4];
    const float* b1  = (const float*)d_in[5];
    const float* w2  = (const float*)d_in[6];
    const float* b2  = (const float*)d_in[7];
    const float* Wih = (const float*)d_in[8];
    const float* Whh = (const float*)d_in[9];
    const float* bih = (const float*)d_in[10];
    const float* bhh = (const float*)d_in[11];
    const float* fcW = (const float*)d_in[12];
    const float* fcb = (const float*)d_in[13];
    const float* foW = (const float*)d_in[14];
    const float* fob = (const float*)d_in[15];

    float* hctxT = (float*)d_ws;                    // 256 KB (proven)
    unsigned short* wbf = (unsigned short*)d_out;   // 1.09 MB bf16 weights in d_out scratch
                                                    // (overwritten by out_gemm at the end)

    conv_kernel<<<dim3((WTOTAL + 255) / 256), dim3(256), 0, stream>>>(W1, Whh, Wih, fcW, wbf);
    scan_kernel<<<dim3(BB), dim3(1024), 0, stream>>>(
        inp, yh, h0, c0, W1, b1, w2, b2, bih, bhh, fcb, wbf, hctxT);
    out_gemm<<<dim3(8192 / 32), dim3(256), 0, stream>>>(hctxT, foW, fob, (float*)d_out);
}